// Round 1
// baseline (1824.478 us; speedup 1.0000x reference)
//
#include <hip/hip_runtime.h>
#include <math.h>

// GLIFR (BNNFC) : B=32, T=1000, IN=256, H=512, OUT=128, A=2, DELAY=20
// Decomposition:
//   1) SYN[t][b][h]  = input[b][t][:] @ W_iv          (one big GEMM, parallel)
//   2) for blk k=0..49 (20 steps each):
//        SYN[t] += F[t-20] @ W_lat    (one [640x512x512] GEMM per blk, k>0)
//        20 sequential elementwise steps, one thread per (b,h), state in regs
//   3) out[b][t][:] = F[t][b][:] @ out_w + out_b      (one big GEMM, parallel)

constexpr int Bsz   = 32;
constexpr int Tn    = 1000;
constexpr int INn   = 256;
constexpr int Hn    = 512;
constexpr int OUTn  = 128;
constexpr int DELAY = 20;
constexpr int NBLK  = Tn / DELAY;   // 50
constexpr float DTc = 0.05f;
constexpr float Rc  = 0.1f;

__device__ __forceinline__ float sigmoidf_(float x) {
    return 1.0f / (1.0f + expf(-x));
}

// ---------------------------------------------------------------------------
// fp32 tiled GEMM, 64x64 tile, BK=16, 256 threads, 4x4 accum per thread.
// MODE_A: 0 -> A row m at A + m*K
//         1 -> A row m=(t*32+b) maps to input[(b*Tn + t)*K]   (input is [B,T,IN])
// MODE_C: 0 -> C row m at C + m*N
//         1 -> C row m=(t*32+b) maps to out[(b*Tn + t)*N]     (out is [B,T,OUT])
// All dims here are exact multiples of tile sizes (32000/640 x 512/128), so no
// bounds checks.
// ---------------------------------------------------------------------------
template<int MODE_A, int MODE_C, bool ACCUM, bool BIAS>
__global__ __launch_bounds__(256) void gemm64(
    const float* __restrict__ A, const float* __restrict__ B,
    float* __restrict__ C, const float* __restrict__ bias,
    int M, int N, int K)
{
    constexpr int BM = 64, BN = 64, BK = 16;
    __shared__ float As[BK][BM + 4];   // +4 pad: conflict-free transpose store, 16B-aligned rows
    __shared__ float Bs[BK][BN];

    const int tid = threadIdx.x;
    const int m0 = blockIdx.x * BM;
    const int n0 = blockIdx.y * BN;
    const int ty = tid >> 4;          // 0..15
    const int tx = tid & 15;          // 0..15

    // A loader: lane k = tid&15, row = tid>>4 (+r*16)
    const int la_k = tid & 15;
    const int la_m = tid >> 4;
    // B loader: lane n = tid&63, k = tid>>6 (+r*4)
    const int lb_n = tid & 63;
    const int lb_k = tid >> 6;

    long arow[4];
#pragma unroll
    for (int r = 0; r < 4; ++r) {
        int m = m0 + la_m + r * 16;
        if (MODE_A == 0) arow[r] = (long)m * K;
        else             arow[r] = ((long)(m & 31) * Tn + (m >> 5)) * (long)K;
    }

    float acc[4][4] = {};

    for (int k0 = 0; k0 < K; k0 += BK) {
#pragma unroll
        for (int r = 0; r < 4; ++r) {
            As[la_k][la_m + r * 16] = A[arow[r] + k0 + la_k];
        }
#pragma unroll
        for (int r = 0; r < 4; ++r) {
            int kk = lb_k + r * 4;
            Bs[kk][lb_n] = B[(long)(k0 + kk) * N + n0 + lb_n];
        }
        __syncthreads();
#pragma unroll
        for (int kk = 0; kk < BK; ++kk) {
            float a[4], b[4];
#pragma unroll
            for (int i = 0; i < 4; ++i) a[i] = As[kk][ty * 4 + i];
#pragma unroll
            for (int j = 0; j < 4; ++j) b[j] = Bs[kk][tx * 4 + j];
#pragma unroll
            for (int i = 0; i < 4; ++i)
#pragma unroll
                for (int j = 0; j < 4; ++j)
                    acc[i][j] = fmaf(a[i], b[j], acc[i][j]);
        }
        __syncthreads();
    }

#pragma unroll
    for (int i = 0; i < 4; ++i) {
        int m = m0 + ty * 4 + i;
        long crow;
        if (MODE_C == 0) crow = (long)m * N;
        else             crow = ((long)(m & 31) * Tn + (m >> 5)) * (long)N;
#pragma unroll
        for (int j = 0; j < 4; ++j) {
            int n = n0 + tx * 4 + j;
            float v = acc[i][j];
            if (BIAS) v += bias[n];
            if (ACCUM) C[crow + n] += v;
            else       C[crow + n] = v;
        }
    }
}

// ---------------------------------------------------------------------------
// Elementwise recurrence: 20 steps, one thread per (b,h). State in registers.
// asc/volt/firing updates are purely per-element; no sync needed.
// ---------------------------------------------------------------------------
__global__ __launch_bounds__(256) void ew_step20(
    const float* __restrict__ syn,      // SYN + t0*B*H : [20][B][H]
    float* __restrict__ Fout,           // F   + t0*B*H : [20][B][H]
    float* __restrict__ volt_s,         // [B*H]
    float* __restrict__ firing_s,       // [B*H]
    float* __restrict__ asc_s,          // [A][B*H]
    const float* __restrict__ trans_k_m,   // [H]
    const float* __restrict__ thresh,      // [H]
    const float* __restrict__ asc_amp,     // [A][H]
    const float* __restrict__ trans_asc_r, // [A][H]
    const float* __restrict__ trans_k_asc, // [A][H]
    int first)
{
    const int idx = blockIdx.x * 256 + threadIdx.x;   // b*H + h
    const int h = idx & (Hn - 1);

    const float dkm   = sigmoidf_(trans_k_m[h]);        // DT * k_m
    const float th    = thresh[h];
    const float amp0  = asc_amp[h];
    const float amp1  = asc_amp[Hn + h];
    const float r0    = 1.0f - 2.0f * sigmoidf_(trans_asc_r[h]);
    const float r1    = 1.0f - 2.0f * sigmoidf_(trans_asc_r[Hn + h]);
    const float dka0  = sigmoidf_(trans_k_asc[h]);      // DT * k_asc
    const float dka1  = sigmoidf_(trans_k_asc[Hn + h]);
    const float dkmR  = dkm * Rc;

    float volt, firing, asc0, asc1;
    if (first) {
        volt = 0.f; firing = 0.f; asc0 = 0.f; asc1 = 0.f;
    } else {
        volt   = volt_s[idx];
        firing = firing_s[idx];
        asc0   = asc_s[idx];
        asc1   = asc_s[Bsz * Hn + idx];
    }

#pragma unroll
    for (int s = 0; s < DELAY; ++s) {
        float sy = syn[s * Bsz * Hn + idx];
        // asc = (asc_r*asc + asc_amp)*firing*DT + asc*(1 - DT*k_asc)
        asc0 = asc0 * (r0 * firing * DTc + (1.0f - dka0)) + amp0 * firing * DTc;
        asc1 = asc1 * (r1 * firing * DTc + (1.0f - dka1)) + amp1 * firing * DTc;
        // volt = volt*(1 - DT*k_m - firing) + DT*k_m*R*(syn + asc_sum)
        volt = volt * (1.0f - dkm - firing) + dkmR * (sy + asc0 + asc1);
        firing = sigmoidf_(volt - th);
        Fout[s * Bsz * Hn + idx] = firing;
    }

    volt_s[idx] = volt;
    firing_s[idx] = firing;
    asc_s[idx] = asc0;
    asc_s[Bsz * Hn + idx] = asc1;
}

extern "C" void kernel_launch(void* const* d_in, const int* in_sizes, int n_in,
                              void* d_out, int out_size, void* d_ws, size_t ws_size,
                              hipStream_t stream) {
    const float* input = (const float*)d_in[0];   // [B,T,IN]
    const float* w_iv  = (const float*)d_in[1];   // [IN,H]
    const float* w_lat = (const float*)d_in[2];   // [H,H]
    const float* thr   = (const float*)d_in[3];   // [1,H]
    const float* tkm   = (const float*)d_in[4];   // [1,H]
    const float* aamp  = (const float*)d_in[5];   // [A,1,H]
    const float* tascr = (const float*)d_in[6];   // [A,1,H]
    const float* tkasc = (const float*)d_in[7];   // [A,1,H]
    const float* outw  = (const float*)d_in[8];   // [H,OUT]
    const float* outb  = (const float*)d_in[9];   // [OUT]
    float* out = (float*)d_out;                   // [B,T,OUT]

    const size_t TBH = (size_t)Tn * Bsz * Hn;     // 16,384,000
    float* SYN      = (float*)d_ws;               // [T][B][H]
    float* F        = SYN + TBH;                  // [T][B][H]
    float* volt_s   = F + TBH;                    // [B*H]
    float* firing_s = volt_s + Bsz * Hn;
    float* asc_s    = firing_s + Bsz * Hn;        // [A][B*H]

    const int MTB = Tn * Bsz;                     // 32000

    // Phase 1: feedforward GEMM into SYN (time-major [T][B][H])
    {
        dim3 g(MTB / 64, Hn / 64);
        gemm64<1, 0, false, false><<<g, 256, 0, stream>>>(input, w_iv, SYN, nullptr,
                                                          MTB, Hn, INn);
    }

    // Phase 2: 50 blocks of 20 steps
    for (int k = 0; k < NBLK; ++k) {
        if (k > 0) {
            dim3 g((DELAY * Bsz) / 64, Hn / 64);  // 10 x 8
            gemm64<0, 0, true, false><<<g, 256, 0, stream>>>(
                F + (size_t)(k - 1) * DELAY * Bsz * Hn, w_lat,
                SYN + (size_t)k * DELAY * Bsz * Hn, nullptr,
                DELAY * Bsz, Hn, Hn);
        }
        ew_step20<<<(Bsz * Hn) / 256, 256, 0, stream>>>(
            SYN + (size_t)k * DELAY * Bsz * Hn,
            F + (size_t)k * DELAY * Bsz * Hn,
            volt_s, firing_s, asc_s,
            tkm, thr, aamp, tascr, tkasc, k == 0);
    }

    // Phase 3: output projection, writes [B,T,OUT]
    {
        dim3 g(MTB / 64, OUTn / 64);              // 500 x 2
        gemm64<0, 1, false, true><<<g, 256, 0, stream>>>(F, outw, out, outb,
                                                         MTB, OUTn, Hn);
    }
}

// Round 2
// 1799.234 us; speedup vs baseline: 1.0140x; 1.0140x over previous
//
#include <hip/hip_runtime.h>
#include <math.h>

// GLIFR (BNNFC) : B=32, T=1000, IN=256, H=512, OUT=128, A=2, DELAY=20
//   1) SYN[t][b][h]  = input[b][t][:] @ W_iv          (one big GEMM, parallel)
//   2) for blk k=0..49 (20 steps each):
//        P[0..3]     = split-K partials of F[blk k-1] @ W_lat   (320 blocks)
//        ew: sy = SYN + sum(P); 20 sequential steps in registers
//   3) out[b][t][:] = F[t][b][:] @ out_w + out_b      (one big GEMM, parallel)

constexpr int Bsz   = 32;
constexpr int Tn    = 1000;
constexpr int INn   = 256;
constexpr int Hn    = 512;
constexpr int OUTn  = 128;
constexpr int DELAY = 20;
constexpr int NBLK  = Tn / DELAY;   // 50
constexpr float DTc = 0.05f;
constexpr float Rc  = 0.1f;

constexpr int BH  = Bsz * Hn;            // 16384
constexpr int MST = DELAY * Bsz;         // 640 rows per stage
constexpr long PSTRIDE = (long)MST * Hn; // 327680 elements per split-K partial

__device__ __forceinline__ float sigmoidf_(float x) {
    return 1.0f / (1.0f + expf(-x));
}

// ---------------------------------------------------------------------------
// fp32 tiled GEMM, 64x64 tile, BK=16, 256 threads, 4x4 accum, float4 loads.
// MODE_A: 0 -> A row m at A + m*K
//         1 -> A row m=(t*32+b) maps to input[(b*Tn + t)*K]   (input is [B,T,IN])
// MODE_C: 0 -> C row m at C + m*N
//         1 -> C row m=(t*32+b) maps to out[(b*Tn + t)*N]     (out is [B,T,OUT])
// SPLIT:  gridDim.z-way split of K; C shifted by z*M*N (partials, no accum)
// ---------------------------------------------------------------------------
template<int MODE_A, int MODE_C, bool BIAS, bool SPLIT>
__global__ __launch_bounds__(256) void gemm64(
    const float* __restrict__ A, const float* __restrict__ B,
    float* __restrict__ C, const float* __restrict__ bias,
    int M, int N, int K)
{
    constexpr int BM = 64, BN = 64, BK = 16;
    __shared__ float As[BK][BM + 4];
    __shared__ float Bs[BK][BN];

    const int tid = threadIdx.x;
    const int m0 = blockIdx.x * BM;
    const int n0 = blockIdx.y * BN;

    int kb = 0, kc = K;
    if (SPLIT) {
        kc = K / gridDim.z;
        kb = blockIdx.z * kc;
        C += (size_t)blockIdx.z * (size_t)M * N;
    }

    // A loader: thread t -> row (t>>2), k-quad (t&3)*4   (64 x 16 tile)
    const int la_m  = tid >> 2;
    const int la_kq = (tid & 3) * 4;
    long arow;
    if (MODE_A == 0) arow = (long)(m0 + la_m) * K;
    else {
        int m = m0 + la_m;
        arow = ((long)(m & 31) * Tn + (m >> 5)) * (long)K;
    }
    // B loader: thread t -> k row (t>>4), col (t&15)*4   (16 x 64 tile)
    const int lb_k = tid >> 4;
    const int lb_n = (tid & 15) * 4;

    const int ty = tid >> 4;          // 0..15
    const int tx = tid & 15;          // 0..15

    float acc[4][4] = {};

    for (int k0 = kb; k0 < kb + kc; k0 += BK) {
        float4 av = *(const float4*)&A[arow + k0 + la_kq];
        As[la_kq + 0][la_m] = av.x;
        As[la_kq + 1][la_m] = av.y;
        As[la_kq + 2][la_m] = av.z;
        As[la_kq + 3][la_m] = av.w;
        *(float4*)&Bs[lb_k][lb_n] =
            *(const float4*)&B[(long)(k0 + lb_k) * N + n0 + lb_n];
        __syncthreads();
#pragma unroll
        for (int kk = 0; kk < BK; ++kk) {
            float a[4], b[4];
#pragma unroll
            for (int i = 0; i < 4; ++i) a[i] = As[kk][ty * 4 + i];
#pragma unroll
            for (int j = 0; j < 4; ++j) b[j] = Bs[kk][tx * 4 + j];
#pragma unroll
            for (int i = 0; i < 4; ++i)
#pragma unroll
                for (int j = 0; j < 4; ++j)
                    acc[i][j] = fmaf(a[i], b[j], acc[i][j]);
        }
        __syncthreads();
    }

    float4 bv;
    if (BIAS) bv = *(const float4*)&bias[n0 + tx * 4];
#pragma unroll
    for (int i = 0; i < 4; ++i) {
        int m = m0 + ty * 4 + i;
        long crow;
        if (MODE_C == 0) crow = (long)m * N;
        else             crow = ((long)(m & 31) * Tn + (m >> 5)) * (long)N;
        float4 v = make_float4(acc[i][0], acc[i][1], acc[i][2], acc[i][3]);
        if (BIAS) { v.x += bv.x; v.y += bv.y; v.z += bv.z; v.w += bv.w; }
        *(float4*)&C[crow + n0 + tx * 4] = v;
    }
}

// ---------------------------------------------------------------------------
// Elementwise recurrence: 20 steps, one thread per (b,h). All syn loads are
// issued up-front (independent), then the serial chain runs in registers.
// ---------------------------------------------------------------------------
template<bool FIRST>
__global__ __launch_bounds__(256) void ew_step20(
    const float* __restrict__ syn,      // SYN + stage offset : [20][B][H]
    const float* __restrict__ P,        // [4][20*B][H] split-K lateral partials
    float* __restrict__ Fout,           // F + stage offset : [20][B][H]
    float* __restrict__ volt_s,         // [B*H]
    float* __restrict__ firing_s,       // [B*H]
    float* __restrict__ asc_s,          // [A][B*H]
    const float* __restrict__ trans_k_m,   // [H]
    const float* __restrict__ thresh,      // [H]
    const float* __restrict__ asc_amp,     // [A][H]
    const float* __restrict__ trans_asc_r, // [A][H]
    const float* __restrict__ trans_k_asc) // [A][H]
{
    const int idx = blockIdx.x * 256 + threadIdx.x;   // b*H + h
    const int h = idx & (Hn - 1);

    // Up-front independent loads: total syn per step (ff + 4 partials).
    float sy[DELAY];
#pragma unroll
    for (int s = 0; s < DELAY; ++s) {
        float v = syn[(long)s * BH + idx];
        if (!FIRST) {
            long o = (long)s * BH + idx;
            v += P[o] + P[PSTRIDE + o] + P[2 * PSTRIDE + o] + P[3 * PSTRIDE + o];
        }
        sy[s] = v;
    }

    const float dkm   = sigmoidf_(trans_k_m[h]);        // DT * k_m
    const float th    = thresh[h];
    const float amp0  = asc_amp[h];
    const float amp1  = asc_amp[Hn + h];
    const float r0    = 1.0f - 2.0f * sigmoidf_(trans_asc_r[h]);
    const float r1    = 1.0f - 2.0f * sigmoidf_(trans_asc_r[Hn + h]);
    const float dka0  = sigmoidf_(trans_k_asc[h]);      // DT * k_asc
    const float dka1  = sigmoidf_(trans_k_asc[Hn + h]);
    const float dkmR  = dkm * Rc;

    float volt, firing, asc0, asc1;
    if (FIRST) {
        volt = 0.f; firing = 0.f; asc0 = 0.f; asc1 = 0.f;
    } else {
        volt   = volt_s[idx];
        firing = firing_s[idx];
        asc0   = asc_s[idx];
        asc1   = asc_s[BH + idx];
    }

#pragma unroll
    for (int s = 0; s < DELAY; ++s) {
        asc0 = asc0 * (r0 * firing * DTc + (1.0f - dka0)) + amp0 * firing * DTc;
        asc1 = asc1 * (r1 * firing * DTc + (1.0f - dka1)) + amp1 * firing * DTc;
        volt = volt * (1.0f - dkm - firing) + dkmR * (sy[s] + asc0 + asc1);
        firing = sigmoidf_(volt - th);
        Fout[(long)s * BH + idx] = firing;
    }

    volt_s[idx] = volt;
    firing_s[idx] = firing;
    asc_s[idx] = asc0;
    asc_s[BH + idx] = asc1;
}

extern "C" void kernel_launch(void* const* d_in, const int* in_sizes, int n_in,
                              void* d_out, int out_size, void* d_ws, size_t ws_size,
                              hipStream_t stream) {
    const float* input = (const float*)d_in[0];   // [B,T,IN]
    const float* w_iv  = (const float*)d_in[1];   // [IN,H]
    const float* w_lat = (const float*)d_in[2];   // [H,H]
    const float* thr   = (const float*)d_in[3];   // [1,H]
    const float* tkm   = (const float*)d_in[4];   // [1,H]
    const float* aamp  = (const float*)d_in[5];   // [A,1,H]
    const float* tascr = (const float*)d_in[6];   // [A,1,H]
    const float* tkasc = (const float*)d_in[7];   // [A,1,H]
    const float* outw  = (const float*)d_in[8];   // [H,OUT]
    const float* outb  = (const float*)d_in[9];   // [OUT]
    float* out = (float*)d_out;                   // [B,T,OUT]

    const size_t TBH = (size_t)Tn * BH;           // 16,384,000
    float* SYN      = (float*)d_ws;               // [T][B][H]
    float* F        = SYN + TBH;                  // [T][B][H]
    float* volt_s   = F + TBH;                    // [B*H]
    float* firing_s = volt_s + BH;
    float* asc_s    = firing_s + BH;              // [A][B*H]
    float* P        = asc_s + 2 * BH;             // [4][640][H] split-K partials

    const int MTB = Tn * Bsz;                     // 32000

    // Phase 1: feedforward GEMM into SYN (time-major [T][B][H])
    {
        dim3 g(MTB / 64, Hn / 64);
        gemm64<1, 0, false, false><<<g, 256, 0, stream>>>(input, w_iv, SYN, nullptr,
                                                          MTB, Hn, INn);
    }

    // Phase 2: 50 stages of 20 steps
    const size_t stage = (size_t)DELAY * BH;      // 327680
    for (int k = 0; k < NBLK; ++k) {
        if (k > 0) {
            dim3 g(MST / 64, Hn / 64, 4);         // 10 x 8 x 4 = 320 blocks
            gemm64<0, 0, false, true><<<g, 256, 0, stream>>>(
                F + (size_t)(k - 1) * stage, w_lat, P, nullptr,
                MST, Hn, Hn);
            ew_step20<false><<<BH / 256, 256, 0, stream>>>(
                SYN + (size_t)k * stage, P, F + (size_t)k * stage,
                volt_s, firing_s, asc_s, tkm, thr, aamp, tascr, tkasc);
        } else {
            ew_step20<true><<<BH / 256, 256, 0, stream>>>(
                SYN, P, F, volt_s, firing_s, asc_s,
                tkm, thr, aamp, tascr, tkasc);
        }
    }

    // Phase 3: output projection, writes [B,T,OUT]
    {
        dim3 g(MTB / 64, OUTn / 64);              // 500 x 2
        gemm64<0, 1, true, false><<<g, 256, 0, stream>>>(F, outw, out, outb,
                                                         MTB, OUTn, Hn);
    }
}

// Round 3
// 1194.029 us; speedup vs baseline: 1.5280x; 1.5069x over previous
//
#include <hip/hip_runtime.h>
#include <math.h>

// GLIFR (BNNFC) : B=32, T=1000, IN=256, H=512, OUT=128, A=2, DELAY=20
//  ph1: SYN[t][b][h] = input @ W_iv                      (fp32 tiled GEMM)
//  cvt: Wt[h][k] = bf16(W_lat[k][h])                     (transpose+convert)
//  ph2: 50 fused stage kernels (bf16 MFMA lateral + elementwise recurrence)
//       F stored bf16, stage-blocked [stage][b][t_local][h]
//  ph3: out = F @ out_w + out_b                          (bf16-A tiled GEMM)

constexpr int Bsz   = 32;
constexpr int Tn    = 1000;
constexpr int INn   = 256;
constexpr int Hn    = 512;
constexpr int OUTn  = 128;
constexpr int DELAY = 20;
constexpr int NBLK  = Tn / DELAY;   // 50
constexpr float DTc = 0.05f;
constexpr float Rc  = 0.1f;
constexpr int BH = Bsz * Hn;             // 16384
constexpr long STG = (long)Bsz * DELAY * Hn;  // 327680 elems per F stage

typedef __attribute__((ext_vector_type(8))) short short8v;  // 8 bf16
typedef __attribute__((ext_vector_type(4))) float f32x4;

__device__ __forceinline__ float sigmoidf_(float x) {
    return 1.0f / (1.0f + expf(-x));
}
__device__ __forceinline__ float bf2f(unsigned short u) {
    return __uint_as_float(((unsigned)u) << 16);
}
__device__ __forceinline__ unsigned short f2bf(float f) {
    unsigned x = __float_as_uint(f);
    return (unsigned short)((x + 0x7fff + ((x >> 16) & 1)) >> 16);  // RNE
}

// ---------------------------------------------------------------------------
// fp32 tiled GEMM (phase 1): 64x64 tile, BK=16, 256 thr, 4x4 micro.
// A row m=(t*32+b) maps to input[(b*Tn + t)*K]  (input is [B,T,IN])
// ---------------------------------------------------------------------------
__global__ __launch_bounds__(256) void gemm_ff(
    const float* __restrict__ A, const float* __restrict__ B,
    float* __restrict__ C, int M, int N, int K)
{
    constexpr int BK = 16;
    __shared__ float As[BK][64 + 4];
    __shared__ float Bs[BK][64];

    const int tid = threadIdx.x;
    const int m0 = blockIdx.x * 64;
    const int n0 = blockIdx.y * 64;

    const int la_m  = tid >> 2;
    const int la_kq = (tid & 3) * 4;
    const int m = m0 + la_m;
    const long arow = ((long)(m & 31) * Tn + (m >> 5)) * (long)K;
    const int lb_k = tid >> 4;
    const int lb_n = (tid & 15) * 4;
    const int ty = tid >> 4, tx = tid & 15;

    float acc[4][4] = {};
    for (int k0 = 0; k0 < K; k0 += BK) {
        float4 av = *(const float4*)&A[arow + k0 + la_kq];
        As[la_kq + 0][la_m] = av.x;
        As[la_kq + 1][la_m] = av.y;
        As[la_kq + 2][la_m] = av.z;
        As[la_kq + 3][la_m] = av.w;
        *(float4*)&Bs[lb_k][lb_n] =
            *(const float4*)&B[(long)(k0 + lb_k) * N + n0 + lb_n];
        __syncthreads();
#pragma unroll
        for (int kk = 0; kk < BK; ++kk) {
            float a[4], b[4];
#pragma unroll
            for (int i = 0; i < 4; ++i) a[i] = As[kk][ty * 4 + i];
#pragma unroll
            for (int j = 0; j < 4; ++j) b[j] = Bs[kk][tx * 4 + j];
#pragma unroll
            for (int i = 0; i < 4; ++i)
#pragma unroll
                for (int j = 0; j < 4; ++j)
                    acc[i][j] = fmaf(a[i], b[j], acc[i][j]);
        }
        __syncthreads();
    }
#pragma unroll
    for (int i = 0; i < 4; ++i) {
        long crow = (long)(m0 + ty * 4 + i) * N;
        *(float4*)&C[crow + n0 + tx * 4] =
            make_float4(acc[i][0], acc[i][1], acc[i][2], acc[i][3]);
    }
}

// ---------------------------------------------------------------------------
// W_lat [512][512] fp32 -> Wt [h][k] bf16 (transposed), 32x32 LDS tiles
// ---------------------------------------------------------------------------
__global__ __launch_bounds__(256) void wlat_cvt(
    const float* __restrict__ W, unsigned short* __restrict__ Wt)
{
    __shared__ float tile[32][33];
    const int tid = threadIdx.x;
    const int bx = blockIdx.x & 15, by = blockIdx.x >> 4;
    const int x = tid & 31, y = tid >> 5;   // 32 x 8
#pragma unroll
    for (int j = 0; j < 4; ++j)
        tile[y + j * 8][x] = W[(long)(by * 32 + y + j * 8) * Hn + bx * 32 + x];
    __syncthreads();
#pragma unroll
    for (int j = 0; j < 4; ++j)
        Wt[(long)(bx * 32 + y + j * 8) * Hn + by * 32 + x] =
            f2bf(tile[x][y + j * 8]);
}

// ---------------------------------------------------------------------------
// Fused stage kernel: lateral bf16-MFMA GEMM (80x64 tile) + ew recurrence.
// Grid 64 blocks (8 rb x 8 cb), 256 threads (4 waves).
//   rb -> b0 = rb*4 (4 b's = 80 rows of r'=b*20+t), cb -> h0 = cb*64.
//   wave w owns col-strip [w*16, w*16+16), 5 M-tiles of 16.
// Fbf stage layout: [b][t_local][h] bf16.
// ---------------------------------------------------------------------------
template<bool FIRST>
__global__ __launch_bounds__(256) void stage_mfma(
    const unsigned short* __restrict__ Fprev,  // stage k-1 (unused if FIRST)
    const float* __restrict__ syn,             // SYN + k*20*BH, [20][32][512]
    unsigned short* __restrict__ Fout,         // stage k
    const unsigned short* __restrict__ Wt,     // [h][k] bf16
    float* __restrict__ volt_s, float* __restrict__ firing_s,
    float* __restrict__ asc_s,
    const float* __restrict__ tkm, const float* __restrict__ thr,
    const float* __restrict__ aamp, const float* __restrict__ tascr,
    const float* __restrict__ tkasc)
{
    __shared__ unsigned short Albs[80 * 128];  // 80 rows x 128 k, swizzled
    __shared__ unsigned short Blbs[64 * 128];  // 64 n    x 128 k, swizzled
    __shared__ float Sy[80][68];               // lateral syn tile (+ff later)

    const int tid = threadIdx.x;
    const int rb = blockIdx.x >> 3;
    const int cb = blockIdx.x & 7;
    const int b0 = rb * 4, h0 = cb * 64;
    const int lane = tid & 63, w = tid >> 6;

    if (!FIRST) {
        f32x4 acc[5] = {};
        uint4 ra[5], rbv[4];

        // flat-index loaders: f -> (row, 16B-chunk kq)
        auto loadA = [&](int kt) {
#pragma unroll
            for (int j = 0; j < 5; ++j) {
                int f = tid + 256 * j; int row = f >> 4, kq = f & 15;
                ra[j] = *(const uint4*)&Fprev[((long)(b0 * DELAY + row)) * Hn
                                              + kt * 128 + kq * 8];
            }
        };
        auto loadB = [&](int kt) {
#pragma unroll
            for (int j = 0; j < 4; ++j) {
                int f = tid + 256 * j; int n = f >> 4, kq = f & 15;
                rbv[j] = *(const uint4*)&Wt[((long)(h0 + n)) * Hn
                                            + kt * 128 + kq * 8];
            }
        };
        auto storeAB = [&]() {
#pragma unroll
            for (int j = 0; j < 5; ++j) {
                int f = tid + 256 * j; int row = f >> 4, kq = f & 15;
                unsigned off = (unsigned)(row * 256 + kq * 16);
                off ^= (unsigned)((row & 7) << 4);
                *(uint4*)((char*)Albs + off) = ra[j];
            }
#pragma unroll
            for (int j = 0; j < 4; ++j) {
                int f = tid + 256 * j; int n = f >> 4, kq = f & 15;
                unsigned off = (unsigned)(n * 256 + kq * 16);
                off ^= (unsigned)((n & 7) << 4);
                *(uint4*)((char*)Blbs + off) = rbv[j];
            }
        };

        loadA(0); loadB(0);
        for (int kt = 0; kt < 4; ++kt) {          // K tiles of 128
            __syncthreads();
            storeAB();
            __syncthreads();
            if (kt < 3) { loadA(kt + 1); loadB(kt + 1); }  // prefetch under MFMA
#pragma unroll
            for (int ks = 0; ks < 4; ++ks) {      // K steps of 32
                short8v bfr;
                {
                    int n = w * 16 + (lane & 15);
                    unsigned off = (unsigned)(n * 256 + ks * 64 + (lane >> 4) * 16);
                    off ^= (unsigned)((n & 7) << 4);
                    bfr = *(const short8v*)((char*)Blbs + off);
                }
#pragma unroll
                for (int mt = 0; mt < 5; ++mt) {
                    int row = mt * 16 + (lane & 15);
                    unsigned off = (unsigned)(row * 256 + ks * 64 + (lane >> 4) * 16);
                    off ^= (unsigned)((row & 7) << 4);
                    short8v afr = *(const short8v*)((char*)Albs + off);
                    acc[mt] = __builtin_amdgcn_mfma_f32_16x16x32_bf16(
                        afr, bfr, acc[mt], 0, 0, 0);
                }
            }
        }
        // epilogue: acc -> Sy.  C layout: col=lane&15, row=(lane>>4)*4+reg
#pragma unroll
        for (int mt = 0; mt < 5; ++mt)
#pragma unroll
            for (int r = 0; r < 4; ++r) {
                int grow = mt * 16 + (lane >> 4) * 4 + r;
                Sy[grow][w * 16 + (lane & 15)] = acc[mt][r];
            }
    }
    __syncthreads();

    // ---- elementwise recurrence: thread = one (b,h) element
    {
        const int bl = tid >> 6, hl = tid & 63;
        const int bb = b0 + bl, h = h0 + hl;
        const int idx = bb * Hn + h;

        const float dkm  = sigmoidf_(tkm[h]);
        const float th   = thr[h];
        const float amp0 = aamp[h],      amp1 = aamp[Hn + h];
        const float r0   = 1.f - 2.f * sigmoidf_(tascr[h]);
        const float r1   = 1.f - 2.f * sigmoidf_(tascr[Hn + h]);
        const float dka0 = sigmoidf_(tkasc[h]);
        const float dka1 = sigmoidf_(tkasc[Hn + h]);
        const float dkmR = dkm * Rc;

        float volt, firing, a0, a1;
        if (FIRST) { volt = firing = a0 = a1 = 0.f; }
        else {
            volt = volt_s[idx]; firing = firing_s[idx];
            a0 = asc_s[idx];    a1 = asc_s[BH + idx];
        }
#pragma unroll
        for (int s = 0; s < DELAY; ++s) {
            float sy = syn[((long)s * Bsz + bb) * Hn + h];
            if (!FIRST) sy += Sy[bl * DELAY + s][hl];
            a0 = a0 * (r0 * firing * DTc + (1.f - dka0)) + amp0 * firing * DTc;
            a1 = a1 * (r1 * firing * DTc + (1.f - dka1)) + amp1 * firing * DTc;
            volt = volt * (1.f - dkm - firing) + dkmR * (sy + a0 + a1);
            firing = sigmoidf_(volt - th);
            Fout[((long)bb * DELAY + s) * Hn + h] = f2bf(firing);
        }
        volt_s[idx] = volt; firing_s[idx] = firing;
        asc_s[idx] = a0;    asc_s[BH + idx] = a1;
    }
}

// ---------------------------------------------------------------------------
// Phase 3: out[b][t][:] = F @ out_w + out_b, A = bf16 stage-blocked F.
// ---------------------------------------------------------------------------
__global__ __launch_bounds__(256) void gemm_out(
    const unsigned short* __restrict__ Fbf, const float* __restrict__ B,
    float* __restrict__ C, const float* __restrict__ bias, int M, int N, int K)
{
    constexpr int BK = 16;
    __shared__ float As[BK][64 + 4];
    __shared__ float Bs[BK][64];

    const int tid = threadIdx.x;
    const int m0 = blockIdx.x * 64;
    const int n0 = blockIdx.y * 64;

    const int la_m  = tid >> 2;
    const int la_kq = (tid & 3) * 4;
    const int m = m0 + la_m;
    const int t = m >> 5, b = m & 31;
    const int ks = t / DELAY, tl = t - ks * DELAY;
    const unsigned short* arow = Fbf + (((long)ks * Bsz + b) * DELAY + tl) * Hn;

    const int lb_k = tid >> 4;
    const int lb_n = (tid & 15) * 4;
    const int ty = tid >> 4, tx = tid & 15;

    float acc[4][4] = {};
    for (int k0 = 0; k0 < K; k0 += BK) {
        const unsigned short* ap = arow + k0 + la_kq;
        As[la_kq + 0][la_m] = bf2f(ap[0]);
        As[la_kq + 1][la_m] = bf2f(ap[1]);
        As[la_kq + 2][la_m] = bf2f(ap[2]);
        As[la_kq + 3][la_m] = bf2f(ap[3]);
        *(float4*)&Bs[lb_k][lb_n] =
            *(const float4*)&B[(long)(k0 + lb_k) * N + n0 + lb_n];
        __syncthreads();
#pragma unroll
        for (int kk = 0; kk < BK; ++kk) {
            float a[4], bvv[4];
#pragma unroll
            for (int i = 0; i < 4; ++i) a[i] = As[kk][ty * 4 + i];
#pragma unroll
            for (int j = 0; j < 4; ++j) bvv[j] = Bs[kk][tx * 4 + j];
#pragma unroll
            for (int i = 0; i < 4; ++i)
#pragma unroll
                for (int j = 0; j < 4; ++j)
                    acc[i][j] = fmaf(a[i], bvv[j], acc[i][j]);
        }
        __syncthreads();
    }
    float4 bv = *(const float4*)&bias[n0 + tx * 4];
#pragma unroll
    for (int i = 0; i < 4; ++i) {
        int mm = m0 + ty * 4 + i;
        long crow = ((long)(mm & 31) * Tn + (mm >> 5)) * (long)N;  // [B,T,OUT]
        float4 v = make_float4(acc[i][0] + bv.x, acc[i][1] + bv.y,
                               acc[i][2] + bv.z, acc[i][3] + bv.w);
        *(float4*)&C[crow + n0 + tx * 4] = v;
    }
}

extern "C" void kernel_launch(void* const* d_in, const int* in_sizes, int n_in,
                              void* d_out, int out_size, void* d_ws, size_t ws_size,
                              hipStream_t stream) {
    const float* input = (const float*)d_in[0];   // [B,T,IN]
    const float* w_iv  = (const float*)d_in[1];   // [IN,H]
    const float* w_lat = (const float*)d_in[2];   // [H,H]
    const float* thr   = (const float*)d_in[3];   // [1,H]
    const float* tkm   = (const float*)d_in[4];   // [1,H]
    const float* aamp  = (const float*)d_in[5];   // [A,1,H]
    const float* tascr = (const float*)d_in[6];   // [A,1,H]
    const float* tkasc = (const float*)d_in[7];   // [A,1,H]
    const float* outw  = (const float*)d_in[8];   // [H,OUT]
    const float* outb  = (const float*)d_in[9];   // [OUT]
    float* out = (float*)d_out;                   // [B,T,OUT]

    const size_t TBH = (size_t)Tn * BH;           // 16,384,000
    float* SYN            = (float*)d_ws;                 // [T][B][H] fp32
    unsigned short* Fbf   = (unsigned short*)(SYN + TBH); // [50][32][20][512] bf16
    unsigned short* Wt    = Fbf + TBH;                    // [512][512] bf16
    float* volt_s   = (float*)(Wt + (size_t)Hn * Hn);
    float* firing_s = volt_s + BH;
    float* asc_s    = firing_s + BH;              // [A][B*H]

    const int MTB = Tn * Bsz;                     // 32000

    // Phase 0: convert + transpose W_lat -> bf16
    wlat_cvt<<<256, 256, 0, stream>>>(w_lat, Wt);

    // Phase 1: feedforward GEMM into SYN (time-major [T][B][H], fp32)
    {
        dim3 g(MTB / 64, Hn / 64);
        gemm_ff<<<g, 256, 0, stream>>>(input, w_iv, SYN, MTB, Hn, INn);
    }

    // Phase 2: 50 fused stages
    const size_t synstage = (size_t)DELAY * BH;
    stage_mfma<true><<<64, 256, 0, stream>>>(
        nullptr, SYN, Fbf, Wt, volt_s, firing_s, asc_s,
        tkm, thr, aamp, tascr, tkasc);
    for (int k = 1; k < NBLK; ++k) {
        stage_mfma<false><<<64, 256, 0, stream>>>(
            Fbf + (size_t)(k - 1) * STG, SYN + (size_t)k * synstage,
            Fbf + (size_t)k * STG, Wt, volt_s, firing_s, asc_s,
            tkm, thr, aamp, tascr, tkasc);
    }

    // Phase 3: output projection, writes [B,T,OUT]
    {
        dim3 g(MTB / 64, OUTn / 64);              // 500 x 2
        gemm_out<<<g, 256, 0, stream>>>(Fbf, outw, out, outb, MTB, OUTn, Hn);
    }
}